// Round 1
// baseline (6034.723 us; speedup 1.0000x reference)
//
#include <hip/hip_runtime.h>
#include <hip/hip_bf16.h>
#include <cstdint>
#include <cstddef>

// Problem constants (B=2, L=2048, D=1024, F=4096, E=8, K=2)
#define B_ 2
#define L_ 2048
#define D_ 1024
#define F_ 4096
#define E_ 8
#define NTOK (B_*L_)   // 4096 tokens

// FFN tiling
#define TM 32          // tokens per tile
#define FC 256         // F-chunk width
#define DC 256         // D-chunk for X staging
#define FH 2048        // F half (2 blocks split F for 2x parallelism)

// ws layout:
// [0,32)    int   cnt[8]        (token count per expert; also freq numerator)
// [32,64)   float psum[8]       (sum of gate softmax probs per expert)
// [256, +8*4096*4)        int   tok_list[8][4096]
// [256+131072, +8*4096*4) float w_list[8][4096]

__device__ __forceinline__ float bflo(uint32_t p){ return __uint_as_float(p << 16); }
__device__ __forceinline__ float bfhi(uint32_t p){ return __uint_as_float(p & 0xffff0000u); }

// ---------------- gating: one wave (64 lanes) per token ----------------
__global__ void gate_kernel(const float* __restrict__ x, const float* __restrict__ Wg,
                            const float* __restrict__ bg, int* __restrict__ cnt,
                            float* __restrict__ psum, int* __restrict__ tok_list,
                            float* __restrict__ w_list)
{
    int token = blockIdx.x;
    int lane  = threadIdx.x;
    const float* xr = x + (size_t)token * D_;

    float acc[E_];
#pragma unroll
    for (int e = 0; e < E_; ++e) acc[e] = 0.f;

    for (int i = 0; i < D_/64; ++i) {
        int d = lane + 64*i;
        float xv = xr[d];
        const float* wr = Wg + (size_t)d * E_;
#pragma unroll
        for (int e = 0; e < E_; ++e) acc[e] += xv * wr[e];
    }
#pragma unroll
    for (int off = 32; off >= 1; off >>= 1) {
#pragma unroll
        for (int e = 0; e < E_; ++e) acc[e] += __shfl_xor(acc[e], off, 64);
    }

    if (lane == 0) {
        float s[E_];
#pragma unroll
        for (int e = 0; e < E_; ++e) s[e] = acc[e] + bg[e];

        // top-2, jax.lax.top_k tie semantics (lower index first on ties)
        int i0 = 0;
#pragma unroll
        for (int e = 1; e < E_; ++e) if (s[e] > s[i0]) i0 = e;
        int i1 = -1;
#pragma unroll
        for (int e = 0; e < E_; ++e) {
            if (e == i0) continue;
            if (i1 < 0 || s[e] > s[i1]) i1 = e;
        }
        // softmax over the two top scores (s[i0] >= s[i1])
        float e1 = expf(s[i1] - s[i0]);
        float w0 = 1.f / (1.f + e1);
        float w1 = e1 * w0;

        // full softmax for prob_mean
        float mx = s[i0];
        float p[E_]; float sum = 0.f;
#pragma unroll
        for (int e = 0; e < E_; ++e) { p[e] = expf(s[e] - mx); sum += p[e]; }
        float inv = 1.f / sum;
#pragma unroll
        for (int e = 0; e < E_; ++e) atomicAdd(&psum[e], p[e] * inv);

        int p0 = atomicAdd(&cnt[i0], 1);
        tok_list[i0*NTOK + p0] = token;  w_list[i0*NTOK + p0] = w0;
        int p1 = atomicAdd(&cnt[i1], 1);
        tok_list[i1*NTOK + p1] = token;  w_list[i1*NTOK + p1] = w1;
    }
}

// ---------------- fused gathered expert FFN ----------------
// grid: E * 128 tiles * 2 F-halves = 2048 blocks, 256 threads.
// Each block: expert e, up to TM=32 gathered tokens, one half of F.
// Per F-chunk: Hc = gelu(X @ W1[:,chunk] + b1); acc += Hc @ W2[chunk,:].
// Epilogue: out[tok] += w * (acc (+ b2 if fhalf==0)) via atomicAdd.
__global__ __launch_bounds__(256, 2) void ffn_kernel(
    const float* __restrict__ x, const float* __restrict__ W1, const float* __restrict__ b1,
    const float* __restrict__ W2, const float* __restrict__ b2,
    const int* __restrict__ cnt, const int* __restrict__ tok_list,
    const float* __restrict__ w_list, float* __restrict__ out)
{
    int bx    = blockIdx.x;
    int e     = bx >> 8;         // 256 blocks per expert
    int rem   = bx & 255;
    int tile  = rem >> 1;
    int fhalf = rem & 1;
    int n     = cnt[e];
    int base  = tile * TM;
    if (base >= n) return;       // uniform early-exit, before any barrier

    __shared__ __hip_bfloat16 Xc[DC][TM];  // 16 KB, layout [d][r] -> contiguous r reads
    __shared__ float Hc[TM][FC];           // 32 KB
    __shared__ int   tok_s[TM];
    __shared__ float w_s[TM];

    int t = threadIdx.x;
    if (t < TM) {
        int idx = base + t;
        if (idx < n) { tok_s[t] = tok_list[e*NTOK + idx]; w_s[t] = w_list[e*NTOK + idx]; }
        else         { tok_s[t] = -1;                      w_s[t] = 0.f; }
    }
    __syncthreads();

    const float* W1e = W1 + (size_t)e * D_ * F_;
    const float* W2e = W2 + (size_t)e * F_ * D_;
    const int r_stage = t >> 3;        // which token row this thread stages
    const int j0      = (t & 7) * 32;  // 32-element d segment within the chunk

    float4 acc[TM];
#pragma unroll
    for (int r = 0; r < TM; ++r) acc[r] = make_float4(0.f, 0.f, 0.f, 0.f);

    const int fbase = fhalf * FH;
    for (int fc = 0; fc < FH; fc += FC) {
        int f0 = fbase + fc;
        float h[TM];
        float b1v = b1[(size_t)e * F_ + f0 + t];
#pragma unroll
        for (int r = 0; r < TM; ++r) h[r] = b1v;

        for (int d0 = 0; d0 < D_; d0 += DC) {
            __syncthreads();   // prior readers of Xc / prior GEMM2 done
            {   // stage X[32 tokens][256 d] as bf16, transposed to [d][r]
                int tk = tok_s[r_stage];
                if (tk >= 0) {
                    const float* xp = x + (size_t)tk * D_ + d0 + j0;
#pragma unroll
                    for (int j = 0; j < 32; j += 4) {
                        float4 v = *(const float4*)(xp + j);
                        Xc[j0+j+0][r_stage] = __float2bfloat16(v.x);
                        Xc[j0+j+1][r_stage] = __float2bfloat16(v.y);
                        Xc[j0+j+2][r_stage] = __float2bfloat16(v.z);
                        Xc[j0+j+3][r_stage] = __float2bfloat16(v.w);
                    }
                } else {
#pragma unroll
                    for (int j = 0; j < 32; ++j) Xc[j0+j][r_stage] = __float2bfloat16(0.f);
                }
            }
            __syncthreads();

            // GEMM1: thread t owns column (f0+t); h[r] += X[r][d] * W1[d][f0+t]
            const float* w1p = W1e + (size_t)d0 * F_ + f0 + t;
#pragma unroll 2
            for (int d = 0; d < DC; ++d) {
                float w1v = *w1p; w1p += F_;
                const uint32_t* xw = (const uint32_t*)(&Xc[d][0]);  // 16 dwords = 32 bf16
#pragma unroll
                for (int q = 0; q < TM/2; ++q) {
                    uint32_t pk = xw[q];
                    h[2*q+0] += bflo(pk) * w1v;
                    h[2*q+1] += bfhi(pk) * w1v;
                }
            }
        }

        // exact GELU, write Hc[r][t] (conflict-free: consecutive t)
#pragma unroll
        for (int r = 0; r < TM; ++r) {
            float v = h[r];
            Hc[r][t] = 0.5f * v * (1.f + erff(v * 0.70710678118654752f));
        }
        __syncthreads();

        // GEMM2: thread t owns out cols 4t..4t+3; acc[r] += Hc[r][f] * W2[f][4t..]
        const float* w2p = W2e + (size_t)f0 * D_ + 4*t;
#pragma unroll 1
        for (int f = 0; f < FC; ++f) {
            float4 wv = *(const float4*)(w2p); w2p += D_;
#pragma unroll
            for (int r = 0; r < TM; ++r) {
                float hv = Hc[r][f];
                acc[r].x += hv * wv.x;
                acc[r].y += hv * wv.y;
                acc[r].z += hv * wv.z;
                acc[r].w += hv * wv.w;
            }
        }
    }

    // epilogue: out[tok] += w * (acc (+ b2 on fhalf 0))
    float4 b2v = *(const float4*)(b2 + (size_t)e * D_ + 4*t);
#pragma unroll
    for (int r = 0; r < TM; ++r) {
        int tk = tok_s[r];
        if (tk < 0) continue;
        float w = w_s[r];
        float4 v = acc[r];
        if (fhalf == 0) { v.x += b2v.x; v.y += b2v.y; v.z += b2v.z; v.w += b2v.w; }
        float* op = out + (size_t)tk * D_ + 4*t;
        atomicAdd(op + 0, w * v.x);
        atomicAdd(op + 1, w * v.y);
        atomicAdd(op + 2, w * v.z);
        atomicAdd(op + 3, w * v.w);
    }
}

// ---------------- load-balance loss ----------------
__global__ void loss_kernel(const int* __restrict__ cnt, const float* __restrict__ psum,
                            float* __restrict__ outp)
{
    float Ls = 0.f;
#pragma unroll
    for (int e = 0; e < E_; ++e)
        Ls += ((float)cnt[e] * (1.f/NTOK)) * (psum[e] * (1.f/NTOK));
    outp[0] = (float)E_ * Ls;
}

extern "C" void kernel_launch(void* const* d_in, const int* in_sizes, int n_in,
                              void* d_out, int out_size, void* d_ws, size_t ws_size,
                              hipStream_t stream)
{
    const float* x  = (const float*)d_in[0];
    const float* Wg = (const float*)d_in[1];
    const float* bg = (const float*)d_in[2];
    const float* W1 = (const float*)d_in[3];
    const float* b1 = (const float*)d_in[4];
    const float* W2 = (const float*)d_in[5];
    const float* b2 = (const float*)d_in[6];
    float* out = (float*)d_out;

    char* ws = (char*)d_ws;
    int*   cnt      = (int*)(ws);
    float* psum     = (float*)(ws + 32);
    int*   tok_list = (int*)(ws + 256);
    float* w_list   = (float*)(ws + 256 + (size_t)E_*NTOK*4);

    // out is poisoned 0xAA before every timed launch: zero it (atomics accumulate into it)
    hipMemsetAsync(d_out, 0, (size_t)out_size * sizeof(float), stream);
    hipMemsetAsync(d_ws, 0, 64, stream);   // cnt[8] + psum[8]

    gate_kernel<<<NTOK, 64, 0, stream>>>(x, Wg, bg, cnt, psum, tok_list, w_list);
    ffn_kernel<<<E_*256, 256, 0, stream>>>(x, W1, b1, W2, b2, cnt, tok_list, w_list, out);
    loss_kernel<<<1, 1, 0, stream>>>(cnt, psum, out + (size_t)NTOK * D_);
}

// Round 2
// 1092.073 us; speedup vs baseline: 5.5259x; 5.5259x over previous
//
#include <hip/hip_runtime.h>
#include <hip/hip_bf16.h>
#include <cstdint>
#include <cstddef>

// B=2, L=2048, D=1024, F=4096, E=8, K=2
#define B_ 2
#define L_ 2048
#define D_ 1024
#define F_ 4096
#define E_ 8
#define NTOK 4096
#define MAXROWS 9216   // sum over experts of pad128(n_e) <= 8192 + 8*127

typedef __hip_bfloat16 bf16;
typedef __attribute__((ext_vector_type(8))) short short8;
typedef __attribute__((ext_vector_type(4))) float floatx4;

typedef const __attribute__((address_space(1))) uint32_t* gptr_t;
typedef __attribute__((address_space(3))) uint32_t* lptr_t;

__device__ __forceinline__ void async_load16(const bf16* gp, bf16* lp) {
    __builtin_amdgcn_global_load_lds((gptr_t)(const void*)gp, (lptr_t)(void*)lp, 16, 0, 0);
}

__device__ __forceinline__ uint16_t bfbits(bf16 h) {
    union { bf16 b; uint16_t u; } v; v.b = h; return v.u;
}
__device__ __forceinline__ uint32_t pack2(float a, float b) {
    return (uint32_t)bfbits(__float2bfloat16(a)) | ((uint32_t)bfbits(__float2bfloat16(b)) << 16);
}

// ---------------- gating: one wave per token ----------------
__global__ void gate_kernel(const float* __restrict__ x, const float* __restrict__ Wg,
                            const float* __restrict__ bg, int* __restrict__ cnt,
                            float* __restrict__ psum, int* __restrict__ tok_list,
                            float* __restrict__ w_list)
{
    int token = blockIdx.x;
    int lane  = threadIdx.x;
    const float* xr = x + (size_t)token * D_;

    float acc[E_];
#pragma unroll
    for (int e = 0; e < E_; ++e) acc[e] = 0.f;
    for (int i = 0; i < D_/64; ++i) {
        int d = lane + 64*i;
        float xv = xr[d];
        const float* wr = Wg + (size_t)d * E_;
#pragma unroll
        for (int e = 0; e < E_; ++e) acc[e] += xv * wr[e];
    }
#pragma unroll
    for (int off = 32; off >= 1; off >>= 1) {
#pragma unroll
        for (int e = 0; e < E_; ++e) acc[e] += __shfl_xor(acc[e], off, 64);
    }
    if (lane == 0) {
        float s[E_];
#pragma unroll
        for (int e = 0; e < E_; ++e) s[e] = acc[e] + bg[e];
        int i0 = 0;
#pragma unroll
        for (int e = 1; e < E_; ++e) if (s[e] > s[i0]) i0 = e;
        int i1 = -1;
#pragma unroll
        for (int e = 0; e < E_; ++e) {
            if (e == i0) continue;
            if (i1 < 0 || s[e] > s[i1]) i1 = e;
        }
        float e1 = expf(s[i1] - s[i0]);
        float w0 = 1.f / (1.f + e1);
        float w1 = e1 * w0;
        float mx = s[i0], p[E_], sum = 0.f;
#pragma unroll
        for (int e = 0; e < E_; ++e) { p[e] = expf(s[e] - mx); sum += p[e]; }
        float inv = 1.f / sum;
#pragma unroll
        for (int e = 0; e < E_; ++e) atomicAdd(&psum[e], p[e] * inv);
        int p0 = atomicAdd(&cnt[i0], 1);
        tok_list[i0*NTOK + p0] = token;  w_list[i0*NTOK + p0] = w0;
        int p1 = atomicAdd(&cnt[i1], 1);
        tok_list[i1*NTOK + p1] = token;  w_list[i1*NTOK + p1] = w1;
    }
}

// ---------------- finalize: padded prefix offsets + loss ----------------
__global__ void finalize_gate_kernel(const int* __restrict__ cnt, const float* __restrict__ psum,
                                     int* __restrict__ off, float* __restrict__ loss_out)
{
    int o = 0; float Ls = 0.f;
    for (int e = 0; e < E_; ++e) {
        off[e] = o;
        o += (cnt[e] + 127) & ~127;
        Ls += (float)cnt[e] * psum[e];
    }
    loss_out[0] = (float)E_ * Ls / ((float)NTOK * (float)NTOK);
}

// ---------------- weight transpose+convert: [R][C] f32 -> [C][R] bf16, per expert ----------------
__global__ __launch_bounds__(256) void transpose_bf16_kernel(
    const float* __restrict__ in, bf16* __restrict__ outp, int R, int C)
{
    int tilesR = R >> 6, tilesC = C >> 6;
    int per = tilesR * tilesC;
    int bx = blockIdx.x;
    int e  = bx / per; int r2 = bx % per;
    int tr = r2 / tilesC, tc = r2 % tilesC;
    int r0 = tr << 6, c0 = tc << 6;
    const float* ip = in  + (size_t)e * R * C;
    bf16*       op = outp + (size_t)e * R * C;

    __shared__ bf16 tile[64][65];
    int t = threadIdx.x;
    int tx = t & 15, ty = t >> 4;
#pragma unroll
    for (int i = 0; i < 4; ++i) {
        int r = ty + (i << 4);
        float4 v = *(const float4*)(ip + (size_t)(r0 + r) * C + c0 + tx*4);
        tile[r][tx*4+0] = __float2bfloat16(v.x);
        tile[r][tx*4+1] = __float2bfloat16(v.y);
        tile[r][tx*4+2] = __float2bfloat16(v.z);
        tile[r][tx*4+3] = __float2bfloat16(v.w);
    }
    __syncthreads();
#pragma unroll
    for (int i = 0; i < 4; ++i) {
        int c = ty + (i << 4);
        uint2 uu;
        uu.x = (uint32_t)bfbits(tile[tx*4+0][c]) | ((uint32_t)bfbits(tile[tx*4+1][c]) << 16);
        uu.y = (uint32_t)bfbits(tile[tx*4+2][c]) | ((uint32_t)bfbits(tile[tx*4+3][c]) << 16);
        *(uint2*)(op + (size_t)(c0 + c) * R + r0 + tx*4) = uu;
    }
}

// ---------------- gather tokens into compacted bf16 A-matrix ----------------
__global__ __launch_bounds__(256) void gather_kernel(
    const float* __restrict__ x, const int* __restrict__ cnt, const int* __restrict__ off,
    const int* __restrict__ tok_list, bf16* __restrict__ Xg)
{
    int bx = blockIdx.x;
    int e  = bx >> 12;        // 4096 slots per expert
    int i  = bx & 4095;
    if (i >= cnt[e]) return;
    int tok = tok_list[e*NTOK + i];
    size_t row = (size_t)(off[e] + i);
    int t = threadIdx.x;
    float4 v = *(const float4*)(x + (size_t)tok * D_ + t*4);
    uint2 uu;
    uu.x = pack2(v.x, v.y);
    uu.y = pack2(v.z, v.w);
    *(uint2*)(Xg + row * D_ + t*4) = uu;
}

// ============ GEMM1: H = gelu(Xg @ W1 + b1), bf16 out ============
// 128x128 tile, BK=64, 256 thr (4 waves in 2x2), XOR-swizzled LDS.
__global__ __launch_bounds__(256) void gemm1_kernel(
    const bf16* __restrict__ Xg, const bf16* __restrict__ W1t,
    const float* __restrict__ b1, const int* __restrict__ cnt,
    const int* __restrict__ off, bf16* __restrict__ H)
{
    int bx = blockIdx.x;
    int e  = bx >> 10;          // 32 mtiles * 32 ntiles per expert
    int r2 = bx & 1023;
    int mtile = r2 >> 5, ntile = r2 & 31;
    int n = cnt[e];
    if (mtile * 128 >= n) return;
    int row0 = off[e] + mtile * 128;
    int f0 = ntile * 128;

    __shared__ bf16 As[128*64];
    __shared__ bf16 Bs[128*64];

    int t = threadIdx.x;
    int wave = t >> 6, lane = t & 63;
    int wm = wave & 1, wn = wave >> 1;
    int q = lane >> 4, ln = lane & 15;
    int sm = lane >> 3, sc = lane & 7;   // staging decode: row-in-group, chunk slot

    const bf16* Abase = Xg  + (size_t)row0 * D_;
    const bf16* Bbase = W1t + ((size_t)e * F_ + f0) * D_;

    floatx4 acc[4][4];
#pragma unroll
    for (int mt = 0; mt < 4; ++mt)
#pragma unroll
        for (int nt = 0; nt < 4; ++nt) acc[mt][nt] = {0.f, 0.f, 0.f, 0.f};

    for (int kt = 0; kt < D_; kt += 64) {
        __syncthreads();
#pragma unroll
        for (int i = 0; i < 4; ++i) {
            int g = wave*4 + i;
            int m = g*8 + sm;
            int ca = sc ^ (m & 7);       // inverse swizzle on global side
            async_load16(Abase + (size_t)m * D_ + kt + ca*8, &As[g*512]);
            async_load16(Bbase + (size_t)m * D_ + kt + ca*8, &Bs[g*512]);
        }
        __syncthreads();
#pragma unroll
        for (int kk = 0; kk < 2; ++kk) {
            short8 av[4], bv[4];
#pragma unroll
            for (int mt = 0; mt < 4; ++mt) {
                int r = wm*64 + mt*16 + ln;
                int cs = (kk*4 + q) ^ (r & 7);
                av[mt] = *(const short8*)&As[r*64 + cs*8];
            }
#pragma unroll
            for (int nt = 0; nt < 4; ++nt) {
                int r = wn*64 + nt*16 + ln;
                int cs = (kk*4 + q) ^ (r & 7);
                bv[nt] = *(const short8*)&Bs[r*64 + cs*8];
            }
#pragma unroll
            for (int mt = 0; mt < 4; ++mt)
#pragma unroll
                for (int nt = 0; nt < 4; ++nt)
                    acc[mt][nt] = __builtin_amdgcn_mfma_f32_16x16x32_bf16(av[mt], bv[nt], acc[mt][nt], 0, 0, 0);
        }
    }

    const float is2 = 0.70710678118654752f;
#pragma unroll
    for (int nt = 0; nt < 4; ++nt) {
        int f = f0 + wn*64 + nt*16 + ln;
        float b1v = b1[(size_t)e * F_ + f];
#pragma unroll
        for (int mt = 0; mt < 4; ++mt) {
            int rl = wm*64 + mt*16 + q*4;
#pragma unroll
            for (int r = 0; r < 4; ++r) {
                float v = acc[mt][nt][r] + b1v;
                v = 0.5f * v * (1.f + erff(v * is2));
                H[(size_t)(row0 + rl + r) * F_ + f] = __float2bfloat16(v);
            }
        }
    }
}

// ============ GEMM2: out[tok] += w * (H @ W2 + b2) ============
__global__ __launch_bounds__(256) void gemm2_kernel(
    const bf16* __restrict__ H, const bf16* __restrict__ W2t,
    const float* __restrict__ b2, const int* __restrict__ cnt, const int* __restrict__ off,
    const int* __restrict__ tok_list, const float* __restrict__ w_list,
    float* __restrict__ out)
{
    int bx = blockIdx.x;
    int e  = bx >> 8;           // 32 mtiles * 8 ntiles per expert
    int r2 = bx & 255;
    int mtile = r2 >> 3, ntile = r2 & 7;
    int n = cnt[e];
    if (mtile * 128 >= n) return;
    int row0 = off[e] + mtile * 128;
    int d0 = ntile * 128;

    __shared__ bf16 As[128*64];
    __shared__ bf16 Bs[128*64];

    int t = threadIdx.x;
    int wave = t >> 6, lane = t & 63;
    int wm = wave & 1, wn = wave >> 1;
    int q = lane >> 4, ln = lane & 15;
    int sm = lane >> 3, sc = lane & 7;

    const bf16* Abase = H   + (size_t)row0 * F_;
    const bf16* Bbase = W2t + ((size_t)e * D_ + d0) * F_;

    floatx4 acc[4][4];
#pragma unroll
    for (int mt = 0; mt < 4; ++mt)
#pragma unroll
        for (int nt = 0; nt < 4; ++nt) acc[mt][nt] = {0.f, 0.f, 0.f, 0.f};

    for (int kt = 0; kt < F_; kt += 64) {
        __syncthreads();
#pragma unroll
        for (int i = 0; i < 4; ++i) {
            int g = wave*4 + i;
            int m = g*8 + sm;
            int ca = sc ^ (m & 7);
            async_load16(Abase + (size_t)m * F_ + kt + ca*8, &As[g*512]);
            async_load16(Bbase + (size_t)m * F_ + kt + ca*8, &Bs[g*512]);
        }
        __syncthreads();
#pragma unroll
        for (int kk = 0; kk < 2; ++kk) {
            short8 av[4], bv[4];
#pragma unroll
            for (int mt = 0; mt < 4; ++mt) {
                int r = wm*64 + mt*16 + ln;
                int cs = (kk*4 + q) ^ (r & 7);
                av[mt] = *(const short8*)&As[r*64 + cs*8];
            }
#pragma unroll
            for (int nt = 0; nt < 4; ++nt) {
                int r = wn*64 + nt*16 + ln;
                int cs = (kk*4 + q) ^ (r & 7);
                bv[nt] = *(const short8*)&Bs[r*64 + cs*8];
            }
#pragma unroll
            for (int mt = 0; mt < 4; ++mt)
#pragma unroll
                for (int nt = 0; nt < 4; ++nt)
                    acc[mt][nt] = __builtin_amdgcn_mfma_f32_16x16x32_bf16(av[mt], bv[nt], acc[mt][nt], 0, 0, 0);
        }
    }

    float b2v[4];
#pragma unroll
    for (int nt = 0; nt < 4; ++nt) b2v[nt] = b2[(size_t)e * D_ + d0 + wn*64 + nt*16 + ln];

#pragma unroll
    for (int mt = 0; mt < 4; ++mt) {
#pragma unroll
        for (int r = 0; r < 4; ++r) {
            int i = mtile*128 + wm*64 + mt*16 + q*4 + r;
            if (i < n) {
                int tok = tok_list[e*NTOK + i];
                float w = w_list[e*NTOK + i];
                float* op = out + (size_t)tok * D_;
#pragma unroll
                for (int nt = 0; nt < 4; ++nt) {
                    int d = d0 + wn*64 + nt*16 + ln;
                    atomicAdd(op + d, w * (acc[mt][nt][r] + b2v[nt]));
                }
            }
        }
    }
}

extern "C" void kernel_launch(void* const* d_in, const int* in_sizes, int n_in,
                              void* d_out, int out_size, void* d_ws, size_t ws_size,
                              hipStream_t stream)
{
    const float* x  = (const float*)d_in[0];
    const float* Wg = (const float*)d_in[1];
    const float* bg = (const float*)d_in[2];
    const float* W1 = (const float*)d_in[3];
    const float* b1 = (const float*)d_in[4];
    const float* W2 = (const float*)d_in[5];
    const float* b2 = (const float*)d_in[6];
    float* out = (float*)d_out;

    char* ws = (char*)d_ws;
    int*   cnt      = (int*)(ws + 0);
    float* psum     = (float*)(ws + 64);
    int*   off      = (int*)(ws + 128);
    int*   tok_list = (int*)(ws + 4096);
    float* w_list   = (float*)(ws + 4096 + 131072);
    size_t o = 1u << 20;
    bf16*  W1t = (bf16*)(ws + o);  o += (size_t)E_ * D_ * F_ * 2;   // 64 MB
    bf16*  W2t = (bf16*)(ws + o);  o += (size_t)E_ * F_ * D_ * 2;   // 64 MB
    bf16*  Xg  = (bf16*)(ws + o);  o += (size_t)MAXROWS * D_ * 2;   // 18 MB
    bf16*  H   = (bf16*)(ws + o);                                    // 72 MB

    hipMemsetAsync(d_out, 0, (size_t)out_size * sizeof(float), stream);
    hipMemsetAsync(d_ws, 0, 128, stream);   // cnt + psum

    // weight transpose+convert (independent of gating)
    transpose_bf16_kernel<<<E_ * 16 * 64, 256, 0, stream>>>(W1, W1t, D_, F_);  // -> [E][F][D]
    transpose_bf16_kernel<<<E_ * 64 * 16, 256, 0, stream>>>(W2, W2t, F_, D_);  // -> [E][D][F]

    gate_kernel<<<NTOK, 64, 0, stream>>>(x, Wg, bg, cnt, psum, tok_list, w_list);
    finalize_gate_kernel<<<1, 1, 0, stream>>>(cnt, psum, off, out + (size_t)NTOK * D_);
    gather_kernel<<<E_ * 4096, 256, 0, stream>>>(x, cnt, off, tok_list, Xg);

    gemm1_kernel<<<E_ * 32 * 32, 256, 0, stream>>>(Xg, W1t, b1, cnt, off, H);
    gemm2_kernel<<<E_ * 32 * 8, 256, 0, stream>>>(H, W2t, b2, cnt, off, tok_list, w_list, out);
}

// Round 3
// 699.666 us; speedup vs baseline: 8.6251x; 1.5608x over previous
//
#include <hip/hip_runtime.h>
#include <hip/hip_bf16.h>
#include <cstdint>
#include <cstddef>

// B=2, L=2048, D=1024, F=4096, E=8, K=2
#define B_ 2
#define L_ 2048
#define D_ 1024
#define F_ 4096
#define E_ 8
#define NTOK 4096
#define MAXROWS 9216   // sum over experts of pad128(n_e) <= 8192 + 8*127

typedef __hip_bfloat16 bf16;
typedef __attribute__((ext_vector_type(8))) short short8;
typedef __attribute__((ext_vector_type(4))) float floatx4;

typedef const __attribute__((address_space(1))) uint32_t* gptr_t;
typedef __attribute__((address_space(3))) uint32_t* lptr_t;

__device__ __forceinline__ void async_load16(const bf16* gp, bf16* lp) {
    __builtin_amdgcn_global_load_lds((gptr_t)(const void*)gp, (lptr_t)(void*)lp, 16, 0, 0);
}

__device__ __forceinline__ uint16_t bfbits(bf16 h) {
    union { bf16 b; uint16_t u; } v; v.b = h; return v.u;
}
__device__ __forceinline__ uint32_t pack2(float a, float b) {
    return (uint32_t)bfbits(__float2bfloat16(a)) | ((uint32_t)bfbits(__float2bfloat16(b)) << 16);
}

// ---------------- gating: 256 blocks x 256 thr, 16 tokens/block (4/wave) ----------------
// Writes per-token packed top-2 ids + weights; accumulates softmax probs in LDS,
// flushes once per block to 128B-padded psum slots (parallel atomic channels).
__global__ __launch_bounds__(256) void gate_kernel(
    const float* __restrict__ x, const float* __restrict__ Wg,
    const float* __restrict__ bg, float* __restrict__ psum_pad,
    uint32_t* __restrict__ top_ids, float* __restrict__ top_w)
{
    __shared__ float psum_l[E_];
    int t = threadIdx.x;
    if (t < E_) psum_l[t] = 0.f;
    __syncthreads();

    int wave = t >> 6, lane = t & 63;
    for (int j = 0; j < 4; ++j) {
        int token = blockIdx.x * 16 + wave * 4 + j;
        const float* xr = x + (size_t)token * D_;

        float acc[E_];
#pragma unroll
        for (int e = 0; e < E_; ++e) acc[e] = 0.f;
        for (int i = 0; i < D_/64; ++i) {
            int d = lane + 64*i;
            float xv = xr[d];
            const float4* wr4 = (const float4*)(Wg + (size_t)d * E_);
            float4 wa = wr4[0], wb = wr4[1];
            acc[0] += xv * wa.x;  acc[1] += xv * wa.y;
            acc[2] += xv * wa.z;  acc[3] += xv * wa.w;
            acc[4] += xv * wb.x;  acc[5] += xv * wb.y;
            acc[6] += xv * wb.z;  acc[7] += xv * wb.w;
        }
#pragma unroll
        for (int off = 32; off >= 1; off >>= 1) {
#pragma unroll
            for (int e = 0; e < E_; ++e) acc[e] += __shfl_xor(acc[e], off, 64);
        }
        if (lane == 0) {
            float s[E_];
#pragma unroll
            for (int e = 0; e < E_; ++e) s[e] = acc[e] + bg[e];
            // top-2, jax.lax.top_k tie semantics (lower index wins ties)
            int i0 = 0;
#pragma unroll
            for (int e = 1; e < E_; ++e) if (s[e] > s[i0]) i0 = e;
            int i1 = -1;
#pragma unroll
            for (int e = 0; e < E_; ++e) {
                if (e == i0) continue;
                if (i1 < 0 || s[e] > s[i1]) i1 = e;
            }
            float e1 = expf(s[i1] - s[i0]);
            float w0 = 1.f / (1.f + e1);
            float w1 = e1 * w0;
            top_ids[token] = (uint32_t)i0 | ((uint32_t)i1 << 8);
            top_w[token]        = w0;
            top_w[NTOK + token] = w1;

            float mx = s[i0], p[E_], sum = 0.f;
#pragma unroll
            for (int e = 0; e < E_; ++e) { p[e] = expf(s[e] - mx); sum += p[e]; }
            float inv = 1.f / sum;
#pragma unroll
            for (int e = 0; e < E_; ++e) atomicAdd(&psum_l[e], p[e] * inv);
        }
    }
    __syncthreads();
    if (t < E_) atomicAdd(&psum_pad[t * 32], psum_l[t]);   // 128B apart -> parallel channels
}

// ---------------- deterministic per-expert compaction (no global position atomics) ----------------
__global__ __launch_bounds__(256) void compact_kernel(
    const uint32_t* __restrict__ top_ids, const float* __restrict__ top_w,
    int* __restrict__ cnt, int* __restrict__ tok_list, float* __restrict__ w_list)
{
    int e = blockIdx.x;
    int t = threadIdx.x, wave = t >> 6, lane = t & 63;
    __shared__ int wcnt[4];
    int base = 0;
    for (int r0 = 0; r0 < NTOK; r0 += 256) {
        int token = r0 + t;
        uint32_t ids = top_ids[token];
        int slot = -1;
        if ((int)(ids & 255u) == e) slot = 0;
        else if ((int)((ids >> 8) & 255u) == e) slot = 1;
        unsigned long long mask = __ballot(slot >= 0);
        int lpos = __popcll(mask & ((1ull << lane) - 1ull));
        if (lane == 0) wcnt[wave] = (int)__popcll(mask);
        __syncthreads();
        int woff = 0, tot = 0;
#pragma unroll
        for (int w2 = 0; w2 < 4; ++w2) { if (w2 < wave) woff += wcnt[w2]; tot += wcnt[w2]; }
        if (slot >= 0) {
            int pos = base + woff + lpos;
            tok_list[e*NTOK + pos] = token;
            w_list[e*NTOK + pos]   = top_w[slot*NTOK + token];
        }
        base += tot;
        __syncthreads();
    }
    if (t == 0) cnt[e] = base;
}

// ---------------- finalize: padded prefix offsets + loss ----------------
__global__ void finalize_gate_kernel(const int* __restrict__ cnt, const float* __restrict__ psum_pad,
                                     int* __restrict__ off, float* __restrict__ loss_out)
{
    int o = 0; float Ls = 0.f;
    for (int e = 0; e < E_; ++e) {
        off[e] = o;
        o += (cnt[e] + 127) & ~127;
        Ls += (float)cnt[e] * psum_pad[e * 32];
    }
    loss_out[0] = (float)E_ * Ls / ((float)NTOK * (float)NTOK);
}

// ---------------- weight transpose+convert: [R][C] f32 -> [C][R] bf16, per expert ----------------
__global__ __launch_bounds__(256) void transpose_bf16_kernel(
    const float* __restrict__ in, bf16* __restrict__ outp, int R, int C)
{
    int tilesR = R >> 6, tilesC = C >> 6;
    int per = tilesR * tilesC;
    int bx = blockIdx.x;
    int e  = bx / per; int r2 = bx % per;
    int tr = r2 / tilesC, tc = r2 % tilesC;
    int r0 = tr << 6, c0 = tc << 6;
    const float* ip = in  + (size_t)e * R * C;
    bf16*       op = outp + (size_t)e * R * C;

    __shared__ bf16 tile[64][65];
    int t = threadIdx.x;
    int tx = t & 15, ty = t >> 4;
#pragma unroll
    for (int i = 0; i < 4; ++i) {
        int r = ty + (i << 4);
        float4 v = *(const float4*)(ip + (size_t)(r0 + r) * C + c0 + tx*4);
        tile[r][tx*4+0] = __float2bfloat16(v.x);
        tile[r][tx*4+1] = __float2bfloat16(v.y);
        tile[r][tx*4+2] = __float2bfloat16(v.z);
        tile[r][tx*4+3] = __float2bfloat16(v.w);
    }
    __syncthreads();
#pragma unroll
    for (int i = 0; i < 4; ++i) {
        int c = ty + (i << 4);
        uint2 uu;
        uu.x = (uint32_t)bfbits(tile[tx*4+0][c]) | ((uint32_t)bfbits(tile[tx*4+1][c]) << 16);
        uu.y = (uint32_t)bfbits(tile[tx*4+2][c]) | ((uint32_t)bfbits(tile[tx*4+3][c]) << 16);
        *(uint2*)(op + (size_t)(c0 + c) * R + r0 + tx*4) = uu;
    }
}

// ---------------- gather tokens into compacted bf16 A-matrix ----------------
__global__ __launch_bounds__(256) void gather_kernel(
    const float* __restrict__ x, const int* __restrict__ cnt, const int* __restrict__ off,
    const int* __restrict__ tok_list, bf16* __restrict__ Xg)
{
    int bx = blockIdx.x;
    int e  = bx >> 12;        // 4096 slots per expert
    int i  = bx & 4095;
    if (i >= cnt[e]) return;
    int tok = tok_list[e*NTOK + i];
    size_t row = (size_t)(off[e] + i);
    int t = threadIdx.x;
    float4 v = *(const float4*)(x + (size_t)tok * D_ + t*4);
    uint2 uu;
    uu.x = pack2(v.x, v.y);
    uu.y = pack2(v.z, v.w);
    *(uint2*)(Xg + row * D_ + t*4) = uu;
}

// ============ GEMM1: H = gelu(Xg @ W1 + b1), bf16 out ============
__global__ __launch_bounds__(256) void gemm1_kernel(
    const bf16* __restrict__ Xg, const bf16* __restrict__ W1t,
    const float* __restrict__ b1, const int* __restrict__ cnt,
    const int* __restrict__ off, bf16* __restrict__ H)
{
    int bx = blockIdx.x;
    int e  = bx >> 10;          // 32 mtiles * 32 ntiles per expert
    int r2 = bx & 1023;
    int mtile = r2 >> 5, ntile = r2 & 31;
    int n = cnt[e];
    if (mtile * 128 >= n) return;
    int row0 = off[e] + mtile * 128;
    int f0 = ntile * 128;

    __shared__ bf16 As[128*64];
    __shared__ bf16 Bs[128*64];

    int t = threadIdx.x;
    int wave = t >> 6, lane = t & 63;
    int wm = wave & 1, wn = wave >> 1;
    int q = lane >> 4, ln = lane & 15;
    int sm = lane >> 3, sc = lane & 7;

    const bf16* Abase = Xg  + (size_t)row0 * D_;
    const bf16* Bbase = W1t + ((size_t)e * F_ + f0) * D_;

    floatx4 acc[4][4];
#pragma unroll
    for (int mt = 0; mt < 4; ++mt)
#pragma unroll
        for (int nt = 0; nt < 4; ++nt) acc[mt][nt] = {0.f, 0.f, 0.f, 0.f};

    for (int kt = 0; kt < D_; kt += 64) {
        __syncthreads();
#pragma unroll
        for (int i = 0; i < 4; ++i) {
            int g = wave*4 + i;
            int m = g*8 + sm;
            int ca = sc ^ (m & 7);
            async_load16(Abase + (size_t)m * D_ + kt + ca*8, &As[g*512]);
            async_load16(Bbase + (size_t)m * D_ + kt + ca*8, &Bs[g*512]);
        }
        __syncthreads();
#pragma unroll
        for (int kk = 0; kk < 2; ++kk) {
            short8 av[4], bv[4];
#pragma unroll
            for (int mt = 0; mt < 4; ++mt) {
                int r = wm*64 + mt*16 + ln;
                int cs = (kk*4 + q) ^ (r & 7);
                av[mt] = *(const short8*)&As[r*64 + cs*8];
            }
#pragma unroll
            for (int nt = 0; nt < 4; ++nt) {
                int r = wn*64 + nt*16 + ln;
                int cs = (kk*4 + q) ^ (r & 7);
                bv[nt] = *(const short8*)&Bs[r*64 + cs*8];
            }
#pragma unroll
            for (int mt = 0; mt < 4; ++mt)
#pragma unroll
                for (int nt = 0; nt < 4; ++nt)
                    acc[mt][nt] = __builtin_amdgcn_mfma_f32_16x16x32_bf16(av[mt], bv[nt], acc[mt][nt], 0, 0, 0);
        }
    }

    const float is2 = 0.70710678118654752f;
#pragma unroll
    for (int nt = 0; nt < 4; ++nt) {
        int f = f0 + wn*64 + nt*16 + ln;
        float b1v = b1[(size_t)e * F_ + f];
#pragma unroll
        for (int mt = 0; mt < 4; ++mt) {
            int rl = wm*64 + mt*16 + q*4;
#pragma unroll
            for (int r = 0; r < 4; ++r) {
                float v = acc[mt][nt][r] + b1v;
                v = 0.5f * v * (1.f + erff(v * is2));
                H[(size_t)(row0 + rl + r) * F_ + f] = __float2bfloat16(v);
            }
        }
    }
}

// ============ GEMM2: out[tok] += w * (H @ W2 + b2) ============
__global__ __launch_bounds__(256) void gemm2_kernel(
    const bf16* __restrict__ H, const bf16* __restrict__ W2t,
    const float* __restrict__ b2, const int* __restrict__ cnt, const int* __restrict__ off,
    const int* __restrict__ tok_list, const float* __restrict__ w_list,
    float* __restrict__ out)
{
    int bx = blockIdx.x;
    int e  = bx >> 8;           // 32 mtiles * 8 ntiles per expert
    int r2 = bx & 255;
    int mtile = r2 >> 3, ntile = r2 & 7;
    int n = cnt[e];
    if (mtile * 128 >= n) return;
    int row0 = off[e] + mtile * 128;
    int d0 = ntile * 128;

    __shared__ bf16 As[128*64];
    __shared__ bf16 Bs[128*64];

    int t = threadIdx.x;
    int wave = t >> 6, lane = t & 63;
    int wm = wave & 1, wn = wave >> 1;
    int q = lane >> 4, ln = lane & 15;
    int sm = lane >> 3, sc = lane & 7;

    const bf16* Abase = H   + (size_t)row0 * F_;
    const bf16* Bbase = W2t + ((size_t)e * D_ + d0) * F_;

    floatx4 acc[4][4];
#pragma unroll
    for (int mt = 0; mt < 4; ++mt)
#pragma unroll
        for (int nt = 0; nt < 4; ++nt) acc[mt][nt] = {0.f, 0.f, 0.f, 0.f};

    for (int kt = 0; kt < F_; kt += 64) {
        __syncthreads();
#pragma unroll
        for (int i = 0; i < 4; ++i) {
            int g = wave*4 + i;
            int m = g*8 + sm;
            int ca = sc ^ (m & 7);
            async_load16(Abase + (size_t)m * F_ + kt + ca*8, &As[g*512]);
            async_load16(Bbase + (size_t)m * F_ + kt + ca*8, &Bs[g*512]);
        }
        __syncthreads();
#pragma unroll
        for (int kk = 0; kk < 2; ++kk) {
            short8 av[4], bv[4];
#pragma unroll
            for (int mt = 0; mt < 4; ++mt) {
                int r = wm*64 + mt*16 + ln;
                int cs = (kk*4 + q) ^ (r & 7);
                av[mt] = *(const short8*)&As[r*64 + cs*8];
            }
#pragma unroll
            for (int nt = 0; nt < 4; ++nt) {
                int r = wn*64 + nt*16 + ln;
                int cs = (kk*4 + q) ^ (r & 7);
                bv[nt] = *(const short8*)&Bs[r*64 + cs*8];
            }
#pragma unroll
            for (int mt = 0; mt < 4; ++mt)
#pragma unroll
                for (int nt = 0; nt < 4; ++nt)
                    acc[mt][nt] = __builtin_amdgcn_mfma_f32_16x16x32_bf16(av[mt], bv[nt], acc[mt][nt], 0, 0, 0);
        }
    }

    float b2v[4];
#pragma unroll
    for (int nt = 0; nt < 4; ++nt) b2v[nt] = b2[(size_t)e * D_ + d0 + wn*64 + nt*16 + ln];

#pragma unroll
    for (int mt = 0; mt < 4; ++mt) {
#pragma unroll
        for (int r = 0; r < 4; ++r) {
            int i = mtile*128 + wm*64 + mt*16 + q*4 + r;
            if (i < n) {
                int tok = tok_list[e*NTOK + i];
                float w = w_list[e*NTOK + i];
                float* op = out + (size_t)tok * D_;
#pragma unroll
                for (int nt = 0; nt < 4; ++nt) {
                    int d = d0 + wn*64 + nt*16 + ln;
                    atomicAdd(op + d, w * (acc[mt][nt][r] + b2v[nt]));
                }
            }
        }
    }
}

extern "C" void kernel_launch(void* const* d_in, const int* in_sizes, int n_in,
                              void* d_out, int out_size, void* d_ws, size_t ws_size,
                              hipStream_t stream)
{
    const float* x  = (const float*)d_in[0];
    const float* Wg = (const float*)d_in[1];
    const float* bg = (const float*)d_in[2];
    const float* W1 = (const float*)d_in[3];
    const float* b1 = (const float*)d_in[4];
    const float* W2 = (const float*)d_in[5];
    const float* b2 = (const float*)d_in[6];
    float* out = (float*)d_out;

    char* ws = (char*)d_ws;
    int*      cnt      = (int*)(ws + 0);
    int*      off      = (int*)(ws + 128);
    float*    psum_pad = (float*)(ws + 1024);            // [8*32] floats, 128B stride
    uint32_t* top_ids  = (uint32_t*)(ws + 8192);         // [NTOK]
    float*    top_w    = (float*)(ws + 8192 + 16384);    // [2][NTOK]
    int*      tok_list = (int*)(ws + 65536);             // [E][NTOK]
    float*    w_list   = (float*)(ws + 65536 + 131072);  // [E][NTOK]
    size_t o = 1u << 20;
    bf16*  W1t = (bf16*)(ws + o);  o += (size_t)E_ * D_ * F_ * 2;   // 64 MB
    bf16*  W2t = (bf16*)(ws + o);  o += (size_t)E_ * F_ * D_ * 2;   // 64 MB
    bf16*  Xg  = (bf16*)(ws + o);  o += (size_t)MAXROWS * D_ * 2;   // 18 MB
    bf16*  H   = (bf16*)(ws + o);                                    // 72 MB

    hipMemsetAsync(d_out, 0, (size_t)out_size * sizeof(float), stream);
    hipMemsetAsync(ws + 1024, 0, 1024, stream);   // psum_pad

    transpose_bf16_kernel<<<E_ * 16 * 64, 256, 0, stream>>>(W1, W1t, D_, F_);  // -> [E][F][D]
    transpose_bf16_kernel<<<E_ * 64 * 16, 256, 0, stream>>>(W2, W2t, F_, D_);  // -> [E][D][F]

    gate_kernel<<<256, 256, 0, stream>>>(x, Wg, bg, psum_pad, top_ids, top_w);
    compact_kernel<<<E_, 256, 0, stream>>>(top_ids, top_w, cnt, tok_list, w_list);
    finalize_gate_kernel<<<1, 1, 0, stream>>>(cnt, psum_pad, off, out + (size_t)NTOK * D_);
    gather_kernel<<<E_ * 4096, 256, 0, stream>>>(x, cnt, off, tok_list, Xg);

    gemm1_kernel<<<E_ * 32 * 32, 256, 0, stream>>>(Xg, W1t, b1, cnt, off, H);
    gemm2_kernel<<<E_ * 32 * 8, 256, 0, stream>>>(H, W2t, b2, cnt, off, tok_list, w_list, out);
}